// Round 1
// baseline (1913.908 us; speedup 1.0000x reference)
//
#include <hip/hip_runtime.h>

#define N_NODES 50000
#define E_EDGES 800000
#define MUL 32

// ---------------------------------------------------------------------------
// Kernel 1: per-node linear maps  s1 = s @ W1_s * lin ;  v1 = v @ W1_v * lin
// 32 lanes per node, 8 nodes per 256-thread block.
// ---------------------------------------------------------------------------
__global__ __launch_bounds__(256) void node_pre(
    const float* __restrict__ nf,
    const float* __restrict__ W1s, const float* __restrict__ W1v,
    float* __restrict__ s1, float* __restrict__ v1)
{
    __shared__ float sW1s[MUL * MUL];
    __shared__ float sW1v[MUL * MUL];
    __shared__ float snf[8][128];
    for (int i = threadIdx.x; i < MUL * MUL; i += 256) { sW1s[i] = W1s[i]; sW1v[i] = W1v[i]; }
    int node0 = blockIdx.x * 8;
    for (int i = threadIdx.x; i < 8 * 128; i += 256) {
        int nn = node0 + (i >> 7);
        snf[i >> 7][i & 127] = (nn < N_NODES) ? nf[(long long)nn * 128 + (i & 127)] : 0.0f;
    }
    __syncthreads();
    int g = threadIdx.x >> 5;
    int v = threadIdx.x & 31;
    int n = node0 + g;
    if (n >= N_NODES) return;
    const float lin = 0.17677669529663687f;  // 1/sqrt(32)
    float acc_s = 0.f, a0 = 0.f, a1 = 0.f, a2 = 0.f;
#pragma unroll
    for (int u = 0; u < MUL; ++u) {
        float su = snf[g][u];
        acc_s += su * sW1s[u * MUL + v];
        float wv = sW1v[u * MUL + v];
        a0 += snf[g][32 + u * 3 + 0] * wv;
        a1 += snf[g][32 + u * 3 + 1] * wv;
        a2 += snf[g][32 + u * 3 + 2] * wv;
    }
    s1[(long long)n * 32 + v] = acc_s * lin;
    v1[(long long)n * 96 + v * 3 + 0] = a0 * lin;
    v1[(long long)n * 96 + v * 3 + 1] = a1 * lin;
    v1[(long long)n * 96 + v * 3 + 2] = a2 * lin;
}

// ---------------------------------------------------------------------------
// Kernel 2: per-edge weight MLP + tensor-product messages, atomic scatter.
// 32 lanes per edge (lane = channel u), 8 edges per 256-thread block.
// n_s layout (N,64): [out_s0 | out_s3].  n_v layout (N,64,3): [out_v1 | out_v2].
// ---------------------------------------------------------------------------
__global__ __launch_bounds__(256) void edge_scatter(
    const float* __restrict__ ee, const float* __restrict__ ea,
    const int* __restrict__ ei,
    const float* __restrict__ s1, const float* __restrict__ v1,
    const float* __restrict__ Wfc1, const float* __restrict__ Wfc2,
    float* __restrict__ n_s, float* __restrict__ n_v)
{
    __shared__ float sWfc1[64];
    __shared__ float sWfc2[1024];
    for (int i = threadIdx.x; i < 64; i += 256) sWfc1[i] = Wfc1[i];
    for (int i = threadIdx.x; i < 1024; i += 256) sWfc2[i] = Wfc2[i];
    __syncthreads();
    int g = threadIdx.x >> 5;
    int u = threadIdx.x & 31;
    long long e = (long long)blockIdx.x * 8 + g;
    if (e >= E_EDGES) return;

    float emb[8];
#pragma unroll
    for (int b = 0; b < 8; ++b) emb[b] = ee[e * 8 + b];
    const float sfc = 0.35355339059327373f;  // 1/sqrt(8)
    float h[8];
#pragma unroll
    for (int k = 0; k < 8; ++k) {
        float acc = 0.f;
#pragma unroll
        for (int b = 0; b < 8; ++b) acc += emb[b] * sWfc1[b * 8 + k];
        acc *= sfc;
        h[k] = acc / (1.f + __expf(-acc));  // silu
    }
    float w0 = 0, w1 = 0, w2 = 0, w3 = 0;
#pragma unroll
    for (int t = 0; t < 8; ++t) {
        float ht = h[t];
        w0 += ht * sWfc2[t * 128 + u];
        w1 += ht * sWfc2[t * 128 + 32 + u];
        w2 += ht * sWfc2[t * 128 + 64 + u];
        w3 += ht * sWfc2[t * 128 + 96 + u];
    }
    w0 *= sfc; w1 *= sfc; w2 *= sfc; w3 *= sfc;

    int ctr = ei[e];
    int nbr = ei[E_EDGES + e];
    float xs  = s1[(long long)nbr * 32 + u];
    float xv0 = v1[(long long)nbr * 96 + u * 3 + 0];
    float xv1 = v1[(long long)nbr * 96 + u * 3 + 1];
    float xv2 = v1[(long long)nbr * 96 + u * 3 + 2];
    float es  = ea[e * 4 + 0];
    float ev0 = ea[e * 4 + 1], ev1 = ea[e * 4 + 2], ev2 = ea[e * 4 + 3];

    float os0 = w0 * xs * es;
    const float is3 = 0.5773502691896258f;  // 1/sqrt(3)
    float os3 = w3 * (xv0 * ev0 + xv1 * ev1 + xv2 * ev2) * is3;
    float t1 = w1 * xs;
    float t2 = w2 * es;

    float* ps = n_s + (long long)ctr * 64;
    atomicAdd(ps + u, os0);
    atomicAdd(ps + 32 + u, os3);
    float* pv = n_v + (long long)ctr * 192;
    atomicAdd(pv + u * 3 + 0, t1 * ev0);
    atomicAdd(pv + u * 3 + 1, t1 * ev1);
    atomicAdd(pv + u * 3 + 2, t1 * ev2);
    atomicAdd(pv + 96 + u * 3 + 0, t2 * xv0);
    atomicAdd(pv + 96 + u * 3 + 1, t2 * xv1);
    atomicAdd(pv + 96 + u * 3 + 2, t2 * xv2);
}

// ---------------------------------------------------------------------------
// Kernel 3: per-node W2 matmuls + self-connection, write output (N,128).
// ---------------------------------------------------------------------------
__global__ __launch_bounds__(256) void node_post(
    const float* __restrict__ nf, const float* __restrict__ attrs,
    const float* __restrict__ n_s, const float* __restrict__ n_v,
    const float* __restrict__ W2s, const float* __restrict__ W2v,
    const float* __restrict__ Wscs, const float* __restrict__ Wscv,
    float* __restrict__ out)
{
    __shared__ float sW2s[64 * 32];
    __shared__ float sW2v[64 * 32];
    __shared__ float sWscs[32 * 4 * 32];
    __shared__ float sWscv[32 * 4 * 32];
    __shared__ float snf[8][128];
    __shared__ float sns[8][64];
    __shared__ float snv[8][192];
    __shared__ float sat[8][4];
    for (int i = threadIdx.x; i < 2048; i += 256) { sW2s[i] = W2s[i]; sW2v[i] = W2v[i]; }
    for (int i = threadIdx.x; i < 4096; i += 256) { sWscs[i] = Wscs[i]; sWscv[i] = Wscv[i]; }
    int node0 = blockIdx.x * 8;
    for (int i = threadIdx.x; i < 8 * 128; i += 256) {
        int nn = node0 + (i >> 7);
        snf[i >> 7][i & 127] = (nn < N_NODES) ? nf[(long long)nn * 128 + (i & 127)] : 0.f;
    }
    for (int i = threadIdx.x; i < 8 * 64; i += 256) {
        int nn = node0 + (i >> 6);
        sns[i >> 6][i & 63] = (nn < N_NODES) ? n_s[(long long)nn * 64 + (i & 63)] : 0.f;
    }
    for (int i = threadIdx.x; i < 8 * 192; i += 256) {
        int nn = node0 + i / 192;
        snv[i / 192][i % 192] = (nn < N_NODES) ? n_v[(long long)nn * 192 + (i % 192)] : 0.f;
    }
    for (int i = threadIdx.x; i < 32; i += 256) {
        int nn = node0 + (i >> 2);
        sat[i >> 2][i & 3] = (nn < N_NODES) ? attrs[nn * 4 + (i & 3)] : 0.f;
    }
    __syncthreads();
    int g = threadIdx.x >> 5, v = threadIdx.x & 31;
    int n = node0 + g;
    if (n >= N_NODES) return;
    float az0 = sat[g][0], az1 = sat[g][1], az2 = sat[g][2], az3 = sat[g][3];
    const float inv  = 0.08838834764831845f;  // 1/sqrt(128)
    const float lin2 = 0.125f;                // 1/sqrt(64)

    float sc_s = 0.f, scv0 = 0.f, scv1 = 0.f, scv2 = 0.f;
#pragma unroll
    for (int u = 0; u < 32; ++u) {
        int base = u * 128 + v;
        float cs = az0 * sWscs[base] + az1 * sWscs[base + 32] + az2 * sWscs[base + 64] + az3 * sWscs[base + 96];
        sc_s += snf[g][u] * cs;
        float cv = az0 * sWscv[base] + az1 * sWscv[base + 32] + az2 * sWscv[base + 64] + az3 * sWscv[base + 96];
        scv0 += snf[g][32 + u * 3 + 0] * cv;
        scv1 += snf[g][32 + u * 3 + 1] * cv;
        scv2 += snf[g][32 + u * 3 + 2] * cv;
    }
    sc_s *= inv; scv0 *= inv; scv1 *= inv; scv2 *= inv;

    float os = 0.f, ov0 = 0.f, ov1 = 0.f, ov2 = 0.f;
#pragma unroll
    for (int u = 0; u < 64; ++u) {
        float w2s = sW2s[u * 32 + v];
        os += sns[g][u] * w2s;
        float w2v = sW2v[u * 32 + v];
        ov0 += snv[g][u * 3 + 0] * w2v;
        ov1 += snv[g][u * 3 + 1] * w2v;
        ov2 += snv[g][u * 3 + 2] * w2v;
    }
    long long ob = (long long)n * 128;
    out[ob + v] = os * lin2 + sc_s;
    out[ob + 32 + v * 3 + 0] = ov0 * lin2 + scv0;
    out[ob + 32 + v * 3 + 1] = ov1 * lin2 + scv1;
    out[ob + 32 + v * 3 + 2] = ov2 * lin2 + scv2;
}

extern "C" void kernel_launch(void* const* d_in, const int* in_sizes, int n_in,
                              void* d_out, int out_size, void* d_ws, size_t ws_size,
                              hipStream_t stream) {
    const float* ee    = (const float*)d_in[0];
    const float* attrs = (const float*)d_in[1];
    const float* nf    = (const float*)d_in[2];
    const int*   ei    = (const int*)d_in[3];
    const float* ea    = (const float*)d_in[4];
    const float* W1s   = (const float*)d_in[5];
    const float* W1v   = (const float*)d_in[6];
    const float* Wfc1  = (const float*)d_in[7];
    const float* Wfc2  = (const float*)d_in[8];
    const float* W2s   = (const float*)d_in[9];
    const float* W2v   = (const float*)d_in[10];
    const float* Wscs  = (const float*)d_in[11];
    const float* Wscv  = (const float*)d_in[12];
    float* out = (float*)d_out;

    float* s1  = (float*)d_ws;                    // N*32
    float* v1  = s1 + (size_t)N_NODES * 32;       // N*96
    float* n_s = v1 + (size_t)N_NODES * 96;       // N*64
    float* n_v = n_s + (size_t)N_NODES * 64;      // N*192

    hipMemsetAsync(n_s, 0, (size_t)N_NODES * (64 + 192) * sizeof(float), stream);
    node_pre<<<(N_NODES + 7) / 8, 256, 0, stream>>>(nf, W1s, W1v, s1, v1);
    edge_scatter<<<(E_EDGES + 7) / 8, 256, 0, stream>>>(ee, ea, ei, s1, v1, Wfc1, Wfc2, n_s, n_v);
    node_post<<<(N_NODES + 7) / 8, 256, 0, stream>>>(nf, attrs, n_s, n_v, W2s, W2v, Wscs, Wscv, out);
}

// Round 2
// 566.287 us; speedup vs baseline: 3.3797x; 3.3797x over previous
//
#include <hip/hip_runtime.h>

#define N_NODES 50000
#define E_EDGES 800000
#define MUL 32
#define CAP 64

// ---------------------------------------------------------------------------
// Kernel 0: per-edge FC1 + silu  ->  h[E][8]   (h includes 1/sqrt(8) scale)
// ---------------------------------------------------------------------------
__global__ __launch_bounds__(256) void edge_h(
    const float* __restrict__ ee, const float* __restrict__ Wfc1,
    float* __restrict__ h)
{
    __shared__ float sW[64];
    if (threadIdx.x < 64) sW[threadIdx.x] = Wfc1[threadIdx.x];
    __syncthreads();
    long long e = (long long)blockIdx.x * 256 + threadIdx.x;
    if (e >= E_EDGES) return;
    const float4* p = (const float4*)(ee + e * 8);
    float4 a = p[0], b = p[1];
    float emb[8] = {a.x, a.y, a.z, a.w, b.x, b.y, b.z, b.w};
    const float sfc = 0.35355339059327373f;  // 1/sqrt(8)
    float out[8];
#pragma unroll
    for (int k = 0; k < 8; ++k) {
        float acc = 0.f;
#pragma unroll
        for (int t = 0; t < 8; ++t) acc += emb[t] * sW[t * 8 + k];
        acc *= sfc;
        out[k] = acc / (1.f + __expf(-acc));  // silu
    }
    float4* ph = (float4*)(h + e * 8);
    ph[0] = make_float4(out[0], out[1], out[2], out[3]);
    ph[1] = make_float4(out[4], out[5], out[6], out[7]);
}

// ---------------------------------------------------------------------------
// Kernel 0b: CSR-ish edge lists per destination (ctr) node.
// ---------------------------------------------------------------------------
__global__ __launch_bounds__(256) void build_lists(
    const int* __restrict__ ei, int* __restrict__ cnt, int* __restrict__ list)
{
    long long e = (long long)blockIdx.x * 256 + threadIdx.x;
    if (e >= E_EDGES) return;
    int c = ei[e];
    int slot = atomicAdd(&cnt[c], 1);
    if (slot < CAP) list[(long long)c * CAP + slot] = (int)e;
}

// ---------------------------------------------------------------------------
// Kernel 1: per-node linear maps  s1 = s @ W1_s * lin ;  v1 = v @ W1_v * lin
// grid-stride, 8 nodes per block-iteration.
// ---------------------------------------------------------------------------
__global__ __launch_bounds__(256) void node_pre(
    const float* __restrict__ nf,
    const float* __restrict__ W1s, const float* __restrict__ W1v,
    float* __restrict__ s1, float* __restrict__ v1)
{
    __shared__ float sW1s[MUL * MUL];
    __shared__ float sW1v[MUL * MUL];
    __shared__ float snf[8][128];
    for (int i = threadIdx.x; i < MUL * MUL; i += 256) { sW1s[i] = W1s[i]; sW1v[i] = W1v[i]; }
    int g = threadIdx.x >> 5;
    int v = threadIdx.x & 31;
    const float lin = 0.17677669529663687f;  // 1/sqrt(32)
    for (int node0 = blockIdx.x * 8; node0 < N_NODES; node0 += gridDim.x * 8) {
        __syncthreads();
        for (int i = threadIdx.x; i < 8 * 128; i += 256) {
            int nn = node0 + (i >> 7);
            snf[i >> 7][i & 127] = (nn < N_NODES) ? nf[(long long)nn * 128 + (i & 127)] : 0.0f;
        }
        __syncthreads();
        int n = node0 + g;
        if (n >= N_NODES) continue;
        float acc_s = 0.f, a0 = 0.f, a1 = 0.f, a2 = 0.f;
#pragma unroll
        for (int u = 0; u < MUL; ++u) {
            float su = snf[g][u];
            acc_s += su * sW1s[u * MUL + v];
            float wv = sW1v[u * MUL + v];
            a0 += snf[g][32 + u * 3 + 0] * wv;
            a1 += snf[g][32 + u * 3 + 1] * wv;
            a2 += snf[g][32 + u * 3 + 2] * wv;
        }
        s1[(long long)n * 32 + v] = acc_s * lin;
        v1[(long long)n * 96 + v * 3 + 0] = a0 * lin;
        v1[(long long)n * 96 + v * 3 + 1] = a1 * lin;
        v1[(long long)n * 96 + v * 3 + 2] = a2 * lin;
    }
}

// ---------------------------------------------------------------------------
// Kernel 2: node-centric gather (atomic-free). One 64-lane wave per node;
// the two 32-lane halves take alternate edges, combined by shfl_xor(32).
// ---------------------------------------------------------------------------
__global__ __launch_bounds__(256) void node_gather(
    const int* __restrict__ cnt, const int* __restrict__ list,
    const int* __restrict__ ei,
    const float* __restrict__ h, const float* __restrict__ ea,
    const float* __restrict__ s1, const float* __restrict__ v1,
    const float* __restrict__ Wfc2,
    float* __restrict__ n_s, float* __restrict__ n_v)
{
    __shared__ float sW[1024];  // Wfc2 (8,128), pre-scaled by 1/sqrt(8)
    const float sfc = 0.35355339059327373f;
    for (int i = threadIdx.x; i < 1024; i += 256) sW[i] = Wfc2[i] * sfc;
    __syncthreads();
    int wid = threadIdx.x >> 6;
    int lane = threadIdx.x & 63;
    int u = lane & 31;
    int half = lane >> 5;
    const float is3 = 0.5773502691896258f;  // 1/sqrt(3)
    for (int n = blockIdx.x * 4 + wid; n < N_NODES; n += gridDim.x * 4) {
        int deg = cnt[n];
        if (deg > CAP) deg = CAP;
        float as0 = 0.f, as3 = 0.f;
        float av10 = 0.f, av11 = 0.f, av12 = 0.f;
        float av20 = 0.f, av21 = 0.f, av22 = 0.f;
        for (int j = half; j < deg; j += 2) {
            int e = list[(long long)n * CAP + j];
            const float4* ph = (const float4*)(h + (long long)e * 8);
            float4 h0 = ph[0], h1 = ph[1];
            float w0 = 0.f, w1 = 0.f, w2 = 0.f, w3 = 0.f;
            float hh[8] = {h0.x, h0.y, h0.z, h0.w, h1.x, h1.y, h1.z, h1.w};
#pragma unroll
            for (int t = 0; t < 8; ++t) {
                float ht = hh[t];
                w0 += ht * sW[t * 128 + u];
                w1 += ht * sW[t * 128 + 32 + u];
                w2 += ht * sW[t * 128 + 64 + u];
                w3 += ht * sW[t * 128 + 96 + u];
            }
            int nbr = ei[E_EDGES + e];
            float xs  = s1[(long long)nbr * 32 + u];
            float xv0 = v1[(long long)nbr * 96 + u * 3 + 0];
            float xv1 = v1[(long long)nbr * 96 + u * 3 + 1];
            float xv2 = v1[(long long)nbr * 96 + u * 3 + 2];
            const float4* pa = (const float4*)(ea + (long long)e * 4);
            float4 eav = pa[0];
            float es = eav.x, ev0 = eav.y, ev1 = eav.z, ev2 = eav.w;
            as0 += w0 * xs * es;
            as3 += w3 * (xv0 * ev0 + xv1 * ev1 + xv2 * ev2);
            float t1 = w1 * xs;
            float t2 = w2 * es;
            av10 += t1 * ev0; av11 += t1 * ev1; av12 += t1 * ev2;
            av20 += t2 * xv0; av21 += t2 * xv1; av22 += t2 * xv2;
        }
        as0  += __shfl_xor(as0, 32);
        as3  += __shfl_xor(as3, 32);
        av10 += __shfl_xor(av10, 32);
        av11 += __shfl_xor(av11, 32);
        av12 += __shfl_xor(av12, 32);
        av20 += __shfl_xor(av20, 32);
        av21 += __shfl_xor(av21, 32);
        av22 += __shfl_xor(av22, 32);
        if (half == 0) {
            n_s[(long long)n * 64 + u] = as0;
            n_s[(long long)n * 64 + 32 + u] = as3 * is3;
            float* pv = n_v + (long long)n * 192;
            pv[u * 3 + 0] = av10; pv[u * 3 + 1] = av11; pv[u * 3 + 2] = av12;
            pv[96 + u * 3 + 0] = av20; pv[96 + u * 3 + 1] = av21; pv[96 + u * 3 + 2] = av22;
        }
    }
}

// ---------------------------------------------------------------------------
// Kernel 3: per-node W2 matmuls + self-connection, write output (N,128).
// grid-stride, 8 nodes per block-iteration.
// ---------------------------------------------------------------------------
__global__ __launch_bounds__(256) void node_post(
    const float* __restrict__ nf, const float* __restrict__ attrs,
    const float* __restrict__ n_s, const float* __restrict__ n_v,
    const float* __restrict__ W2s, const float* __restrict__ W2v,
    const float* __restrict__ Wscs, const float* __restrict__ Wscv,
    float* __restrict__ out)
{
    __shared__ float sW2s[64 * 32];
    __shared__ float sW2v[64 * 32];
    __shared__ float sWscs[32 * 4 * 32];
    __shared__ float sWscv[32 * 4 * 32];
    __shared__ float snf[8][128];
    __shared__ float sns[8][64];
    __shared__ float snv[8][192];
    __shared__ float sat[8][4];
    for (int i = threadIdx.x; i < 2048; i += 256) { sW2s[i] = W2s[i]; sW2v[i] = W2v[i]; }
    for (int i = threadIdx.x; i < 4096; i += 256) { sWscs[i] = Wscs[i]; sWscv[i] = Wscv[i]; }
    int g = threadIdx.x >> 5, v = threadIdx.x & 31;
    const float inv  = 0.08838834764831845f;  // 1/sqrt(128)
    const float lin2 = 0.125f;                // 1/sqrt(64)
    for (int node0 = blockIdx.x * 8; node0 < N_NODES; node0 += gridDim.x * 8) {
        __syncthreads();
        for (int i = threadIdx.x; i < 8 * 128; i += 256) {
            int nn = node0 + (i >> 7);
            snf[i >> 7][i & 127] = (nn < N_NODES) ? nf[(long long)nn * 128 + (i & 127)] : 0.f;
        }
        for (int i = threadIdx.x; i < 8 * 64; i += 256) {
            int nn = node0 + (i >> 6);
            sns[i >> 6][i & 63] = (nn < N_NODES) ? n_s[(long long)nn * 64 + (i & 63)] : 0.f;
        }
        for (int i = threadIdx.x; i < 8 * 192; i += 256) {
            int nn = node0 + i / 192;
            snv[i / 192][i % 192] = (nn < N_NODES) ? n_v[(long long)nn * 192 + (i % 192)] : 0.f;
        }
        for (int i = threadIdx.x; i < 32; i += 256) {
            int nn = node0 + (i >> 2);
            sat[i >> 2][i & 3] = (nn < N_NODES) ? attrs[nn * 4 + (i & 3)] : 0.f;
        }
        __syncthreads();
        int n = node0 + g;
        if (n >= N_NODES) continue;
        float az0 = sat[g][0], az1 = sat[g][1], az2 = sat[g][2], az3 = sat[g][3];

        float sc_s = 0.f, scv0 = 0.f, scv1 = 0.f, scv2 = 0.f;
#pragma unroll
        for (int u = 0; u < 32; ++u) {
            int base = u * 128 + v;
            float cs = az0 * sWscs[base] + az1 * sWscs[base + 32] + az2 * sWscs[base + 64] + az3 * sWscs[base + 96];
            sc_s += snf[g][u] * cs;
            float cv = az0 * sWscv[base] + az1 * sWscv[base + 32] + az2 * sWscv[base + 64] + az3 * sWscv[base + 96];
            scv0 += snf[g][32 + u * 3 + 0] * cv;
            scv1 += snf[g][32 + u * 3 + 1] * cv;
            scv2 += snf[g][32 + u * 3 + 2] * cv;
        }
        sc_s *= inv; scv0 *= inv; scv1 *= inv; scv2 *= inv;

        float os = 0.f, ov0 = 0.f, ov1 = 0.f, ov2 = 0.f;
#pragma unroll
        for (int u = 0; u < 64; ++u) {
            float w2s = sW2s[u * 32 + v];
            os += sns[g][u] * w2s;
            float w2v = sW2v[u * 32 + v];
            ov0 += snv[g][u * 3 + 0] * w2v;
            ov1 += snv[g][u * 3 + 1] * w2v;
            ov2 += snv[g][u * 3 + 2] * w2v;
        }
        long long ob = (long long)n * 128;
        out[ob + v] = os * lin2 + sc_s;
        out[ob + 32 + v * 3 + 0] = ov0 * lin2 + scv0;
        out[ob + 32 + v * 3 + 1] = ov1 * lin2 + scv1;
        out[ob + 32 + v * 3 + 2] = ov2 * lin2 + scv2;
    }
}

extern "C" void kernel_launch(void* const* d_in, const int* in_sizes, int n_in,
                              void* d_out, int out_size, void* d_ws, size_t ws_size,
                              hipStream_t stream) {
    const float* ee    = (const float*)d_in[0];
    const float* attrs = (const float*)d_in[1];
    const float* nf    = (const float*)d_in[2];
    const int*   ei    = (const int*)d_in[3];
    const float* ea    = (const float*)d_in[4];
    const float* W1s   = (const float*)d_in[5];
    const float* W1v   = (const float*)d_in[6];
    const float* Wfc1  = (const float*)d_in[7];
    const float* Wfc2  = (const float*)d_in[8];
    const float* W2s   = (const float*)d_in[9];
    const float* W2v   = (const float*)d_in[10];
    const float* Wscs  = (const float*)d_in[11];
    const float* Wscv  = (const float*)d_in[12];
    float* out = (float*)d_out;

    float* s1  = (float*)d_ws;                       // N*32
    float* v1  = s1 + (size_t)N_NODES * 32;          // N*96
    float* n_s = v1 + (size_t)N_NODES * 96;          // N*64
    float* n_v = n_s + (size_t)N_NODES * 64;         // N*192
    float* h   = n_v + (size_t)N_NODES * 192;        // E*8
    int*   cnt  = (int*)(h + (size_t)E_EDGES * 8);   // N
    int*   list = cnt + N_NODES;                     // N*CAP

    hipMemsetAsync(cnt, 0, (size_t)N_NODES * sizeof(int), stream);
    edge_h<<<(E_EDGES + 255) / 256, 256, 0, stream>>>(ee, Wfc1, h);
    build_lists<<<(E_EDGES + 255) / 256, 256, 0, stream>>>(ei, cnt, list);
    node_pre<<<1024, 256, 0, stream>>>(nf, W1s, W1v, s1, v1);
    node_gather<<<2048, 256, 0, stream>>>(cnt, list, ei, h, ea, s1, v1, Wfc2, n_s, n_v);
    node_post<<<1024, 256, 0, stream>>>(nf, attrs, n_s, n_v, W2s, W2v, Wscs, Wscv, out);
}

// Round 3
// 482.195 us; speedup vs baseline: 3.9692x; 1.1744x over previous
//
#include <hip/hip_runtime.h>

#define N_NODES 50000
#define E_EDGES 800000
#define MUL 32
#define CAP 64

// ---------------------------------------------------------------------------
// Kernel 0: per-edge FC1 + silu -> h[E][8]  (h includes 1/sqrt(8) scale),
// fused with per-ctr edge-list build (one int atomic per edge).
// ---------------------------------------------------------------------------
__global__ __launch_bounds__(256) void edge_prep(
    const float* __restrict__ ee, const float* __restrict__ Wfc1,
    const int* __restrict__ ei,
    float* __restrict__ h, int* __restrict__ cnt, int* __restrict__ list)
{
    __shared__ float sW[64];
    if (threadIdx.x < 64) sW[threadIdx.x] = Wfc1[threadIdx.x];
    __syncthreads();
    long long e = (long long)blockIdx.x * 256 + threadIdx.x;
    if (e >= E_EDGES) return;

    int c = ei[e];
    int slot = atomicAdd(&cnt[c], 1);
    if (slot < CAP) list[(long long)c * CAP + slot] = (int)e;

    const float4* p = (const float4*)(ee + e * 8);
    float4 a = p[0], b = p[1];
    float emb[8] = {a.x, a.y, a.z, a.w, b.x, b.y, b.z, b.w};
    const float sfc = 0.35355339059327373f;  // 1/sqrt(8)
    float out[8];
#pragma unroll
    for (int k = 0; k < 8; ++k) {
        float acc = 0.f;
#pragma unroll
        for (int t = 0; t < 8; ++t) acc += emb[t] * sW[t * 8 + k];
        acc *= sfc;
        out[k] = acc / (1.f + __expf(-acc));  // silu
    }
    float4* ph = (float4*)(h + e * 8);
    ph[0] = make_float4(out[0], out[1], out[2], out[3]);
    ph[1] = make_float4(out[4], out[5], out[6], out[7]);
}

// ---------------------------------------------------------------------------
// Kernel 1: per-node linear maps (s1, v1) fused with self-connection einsum.
// sc result is written directly into out; gather_post later adds the W2 term.
// LDS 44 KB -> 3 blocks/CU.
// ---------------------------------------------------------------------------
__global__ __launch_bounds__(256) void node_pre_sc(
    const float* __restrict__ nf, const float* __restrict__ attrs,
    const float* __restrict__ W1s, const float* __restrict__ W1v,
    const float* __restrict__ Wscs, const float* __restrict__ Wscv,
    float* __restrict__ s1, float* __restrict__ v1, float* __restrict__ out)
{
    __shared__ float sW1s[1024];
    __shared__ float sW1v[1024];
    __shared__ float sWscs[4096];
    __shared__ float sWscv[4096];
    __shared__ float snf[8][128];
    __shared__ float sat[8][4];
    for (int i = threadIdx.x; i < 1024; i += 256) { sW1s[i] = W1s[i]; sW1v[i] = W1v[i]; }
    for (int i = threadIdx.x; i < 4096; i += 256) { sWscs[i] = Wscs[i]; sWscv[i] = Wscv[i]; }
    int g = threadIdx.x >> 5, v = threadIdx.x & 31;
    const float lin = 0.17677669529663687f;   // 1/sqrt(32)
    const float inv = 0.08838834764831845f;   // 1/sqrt(128)
    for (int node0 = blockIdx.x * 8; node0 < N_NODES; node0 += gridDim.x * 8) {
        __syncthreads();
        for (int i = threadIdx.x; i < 8 * 128; i += 256) {
            int nn = node0 + (i >> 7);
            snf[i >> 7][i & 127] = (nn < N_NODES) ? nf[(long long)nn * 128 + (i & 127)] : 0.f;
        }
        if (threadIdx.x < 32) {
            int nn = node0 + (threadIdx.x >> 2);
            sat[threadIdx.x >> 2][threadIdx.x & 3] = (nn < N_NODES) ? attrs[nn * 4 + (threadIdx.x & 3)] : 0.f;
        }
        __syncthreads();
        int n = node0 + g;
        if (n >= N_NODES) continue;
        float az0 = sat[g][0], az1 = sat[g][1], az2 = sat[g][2], az3 = sat[g][3];
        float acc_s = 0.f, a0 = 0.f, a1 = 0.f, a2 = 0.f;
        float scs = 0.f, scv0 = 0.f, scv1 = 0.f, scv2 = 0.f;
#pragma unroll
        for (int u = 0; u < 32; ++u) {
            float su = snf[g][u];
            float x0 = snf[g][32 + u * 3 + 0];
            float x1 = snf[g][32 + u * 3 + 1];
            float x2 = snf[g][32 + u * 3 + 2];
            acc_s += su * sW1s[u * 32 + v];
            float wv = sW1v[u * 32 + v];
            a0 += x0 * wv; a1 += x1 * wv; a2 += x2 * wv;
            int base = u * 128 + v;
            float cs = az0 * sWscs[base] + az1 * sWscs[base + 32] + az2 * sWscs[base + 64] + az3 * sWscs[base + 96];
            scs += su * cs;
            float cv = az0 * sWscv[base] + az1 * sWscv[base + 32] + az2 * sWscv[base + 64] + az3 * sWscv[base + 96];
            scv0 += x0 * cv; scv1 += x1 * cv; scv2 += x2 * cv;
        }
        s1[(long long)n * 32 + v] = acc_s * lin;
        v1[(long long)n * 96 + v * 3 + 0] = a0 * lin;
        v1[(long long)n * 96 + v * 3 + 1] = a1 * lin;
        v1[(long long)n * 96 + v * 3 + 2] = a2 * lin;
        long long ob = (long long)n * 128;
        out[ob + v] = scs * inv;
        out[ob + 32 + v * 3 + 0] = scv0 * inv;
        out[ob + 32 + v * 3 + 1] = scv1 * inv;
        out[ob + 32 + v * 3 + 2] = scv2 * inv;
    }
}

// ---------------------------------------------------------------------------
// Kernel 2: node-centric gather fused with W2 matmul + sc add.
// One wave per node; half-waves take alternate edges; after the edge loop the
// wave's accumulators (= the node's full n_s/n_v) go through a per-wave LDS
// transpose buffer, then W2 is applied and out is RMW'd (sc already there).
// LDS 24 KB -> 6 blocks/CU.
// ---------------------------------------------------------------------------
__global__ __launch_bounds__(256) void gather_post(
    const int* __restrict__ cnt, const int* __restrict__ list,
    const int* __restrict__ ei,
    const float* __restrict__ h, const float* __restrict__ ea,
    const float* __restrict__ s1, const float* __restrict__ v1,
    const float* __restrict__ Wfc2,
    const float* __restrict__ W2s, const float* __restrict__ W2v,
    float* __restrict__ out)
{
    __shared__ float sW[1024];    // Wfc2 (8,128) pre-scaled by 1/sqrt(8)
    __shared__ float sW2s[2048];  // (64,32)
    __shared__ float sW2v[2048];  // (64,32)
    __shared__ float tb[4][256];  // per-wave [n_s(64) | n_v(64x3)]
    const float sfc = 0.35355339059327373f;
    for (int i = threadIdx.x; i < 1024; i += 256) sW[i] = Wfc2[i] * sfc;
    for (int i = threadIdx.x; i < 2048; i += 256) { sW2s[i] = W2s[i]; sW2v[i] = W2v[i]; }
    __syncthreads();
    int wid = threadIdx.x >> 6;
    int lane = threadIdx.x & 63;
    int u = lane & 31;
    int half = lane >> 5;
    const float is3 = 0.5773502691896258f;  // 1/sqrt(3)
    const float lin2 = 0.125f;              // 1/sqrt(64)
    for (int base = blockIdx.x * 4; base < N_NODES; base += gridDim.x * 4) {
        int n = base + wid;
        bool valid = n < N_NODES;
        float as0 = 0.f, as3 = 0.f;
        float av10 = 0.f, av11 = 0.f, av12 = 0.f;
        float av20 = 0.f, av21 = 0.f, av22 = 0.f;
        if (valid) {
            int deg = cnt[n];
            if (deg > CAP) deg = CAP;
            long long lb = (long long)n * CAP;
            int e_cur = 0, nbr_cur = 0;
            if (half < deg) { e_cur = list[lb + half]; nbr_cur = ei[E_EDGES + e_cur]; }
            for (int j = half; j < deg; j += 2) {
                bool more = (j + 2) < deg;
                int e_nxt = more ? list[lb + j + 2] : 0;
                const float4* ph = (const float4*)(h + (long long)e_cur * 8);
                float4 h0 = ph[0], h1 = ph[1];
                const float4* pa = (const float4*)(ea + (long long)e_cur * 4);
                float4 eav = pa[0];
                float xs  = s1[(long long)nbr_cur * 32 + u];
                float xv0 = v1[(long long)nbr_cur * 96 + u * 3 + 0];
                float xv1 = v1[(long long)nbr_cur * 96 + u * 3 + 1];
                float xv2 = v1[(long long)nbr_cur * 96 + u * 3 + 2];
                int nbr_nxt = more ? ei[E_EDGES + e_nxt] : 0;
                float hh[8] = {h0.x, h0.y, h0.z, h0.w, h1.x, h1.y, h1.z, h1.w};
                float w0 = 0.f, w1 = 0.f, w2 = 0.f, w3 = 0.f;
#pragma unroll
                for (int t = 0; t < 8; ++t) {
                    float ht = hh[t];
                    w0 += ht * sW[t * 128 + u];
                    w1 += ht * sW[t * 128 + 32 + u];
                    w2 += ht * sW[t * 128 + 64 + u];
                    w3 += ht * sW[t * 128 + 96 + u];
                }
                float es = eav.x, ev0 = eav.y, ev1 = eav.z, ev2 = eav.w;
                as0 += w0 * xs * es;
                as3 += w3 * (xv0 * ev0 + xv1 * ev1 + xv2 * ev2);
                float t1 = w1 * xs;
                float t2 = w2 * es;
                av10 += t1 * ev0; av11 += t1 * ev1; av12 += t1 * ev2;
                av20 += t2 * xv0; av21 += t2 * xv1; av22 += t2 * xv2;
                e_cur = e_nxt; nbr_cur = nbr_nxt;
            }
            as0  += __shfl_xor(as0, 32);
            as3  += __shfl_xor(as3, 32);
            av10 += __shfl_xor(av10, 32);
            av11 += __shfl_xor(av11, 32);
            av12 += __shfl_xor(av12, 32);
            av20 += __shfl_xor(av20, 32);
            av21 += __shfl_xor(av21, 32);
            av22 += __shfl_xor(av22, 32);
            float* tw = tb[wid];
            if (half == 0) {
                tw[u] = as0;
                tw[64 + u * 3 + 0] = av10;
                tw[64 + u * 3 + 1] = av11;
                tw[64 + u * 3 + 2] = av12;
            } else {
                tw[32 + u] = as3 * is3;
                tw[64 + (32 + u) * 3 + 0] = av20;
                tw[64 + (32 + u) * 3 + 1] = av21;
                tw[64 + (32 + u) * 3 + 2] = av22;
            }
        }
        __syncthreads();
        if (valid) {
            long long ob = (long long)n * 128;
            const float* tw = tb[wid];
            if (half == 0) {
                float sc = out[ob + u];
                float acc = 0.f;
#pragma unroll
                for (int U = 0; U < 64; ++U) acc += tw[U] * sW2s[U * 32 + u];
                out[ob + u] = acc * lin2 + sc;
            } else {
                float sc0 = out[ob + 32 + u * 3 + 0];
                float sc1 = out[ob + 32 + u * 3 + 1];
                float sc2 = out[ob + 32 + u * 3 + 2];
                float b0 = 0.f, b1 = 0.f, b2 = 0.f;
#pragma unroll
                for (int U = 0; U < 64; ++U) {
                    float w = sW2v[U * 32 + u];
                    b0 += tw[64 + U * 3 + 0] * w;
                    b1 += tw[64 + U * 3 + 1] * w;
                    b2 += tw[64 + U * 3 + 2] * w;
                }
                out[ob + 32 + u * 3 + 0] = b0 * lin2 + sc0;
                out[ob + 32 + u * 3 + 1] = b1 * lin2 + sc1;
                out[ob + 32 + u * 3 + 2] = b2 * lin2 + sc2;
            }
        }
        __syncthreads();
    }
}

extern "C" void kernel_launch(void* const* d_in, const int* in_sizes, int n_in,
                              void* d_out, int out_size, void* d_ws, size_t ws_size,
                              hipStream_t stream) {
    const float* ee    = (const float*)d_in[0];
    const float* attrs = (const float*)d_in[1];
    const float* nf    = (const float*)d_in[2];
    const int*   ei    = (const int*)d_in[3];
    const float* ea    = (const float*)d_in[4];
    const float* W1s   = (const float*)d_in[5];
    const float* W1v   = (const float*)d_in[6];
    const float* Wfc1  = (const float*)d_in[7];
    const float* Wfc2  = (const float*)d_in[8];
    const float* W2s   = (const float*)d_in[9];
    const float* W2v   = (const float*)d_in[10];
    const float* Wscs  = (const float*)d_in[11];
    const float* Wscv  = (const float*)d_in[12];
    float* out = (float*)d_out;

    float* s1  = (float*)d_ws;                       // N*32
    float* v1  = s1 + (size_t)N_NODES * 32;          // N*96
    float* h   = v1 + (size_t)N_NODES * 96;          // E*8
    int*   cnt  = (int*)(h + (size_t)E_EDGES * 8);   // N
    int*   list = cnt + N_NODES;                     // N*CAP

    hipMemsetAsync(cnt, 0, (size_t)N_NODES * sizeof(int), stream);
    edge_prep<<<(E_EDGES + 255) / 256, 256, 0, stream>>>(ee, Wfc1, ei, h, cnt, list);
    node_pre_sc<<<768, 256, 0, stream>>>(nf, attrs, W1s, W1v, Wscs, Wscv, s1, v1, out);
    gather_post<<<1536, 256, 0, stream>>>(cnt, list, ei, h, ea, s1, v1, Wfc2, W2s, W2v, out);
}

// Round 5
// 413.259 us; speedup vs baseline: 4.6313x; 1.1668x over previous
//
#include <hip/hip_runtime.h>

#define N_NODES 50000
#define E_EDGES 800000
#define MUL 32
#define CAP 64

// ---------------------------------------------------------------------------
// Kernel 0: per-edge FC1 + silu -> h[E][8]  (h includes 1/sqrt(8) scale),
// fused with per-ctr edge-list build (one int atomic per edge).
// ---------------------------------------------------------------------------
__global__ __launch_bounds__(256) void edge_prep(
    const float* __restrict__ ee, const float* __restrict__ Wfc1,
    const int* __restrict__ ei,
    float* __restrict__ h, int* __restrict__ cnt, int* __restrict__ list)
{
    __shared__ float sW[64];
    if (threadIdx.x < 64) sW[threadIdx.x] = Wfc1[threadIdx.x];
    __syncthreads();
    long long e = (long long)blockIdx.x * 256 + threadIdx.x;
    if (e >= E_EDGES) return;

    int c = ei[e];
    int slot = atomicAdd(&cnt[c], 1);
    if (slot < CAP) list[(long long)c * CAP + slot] = (int)e;

    const float4* p = (const float4*)(ee + e * 8);
    float4 a = p[0], b = p[1];
    float emb[8] = {a.x, a.y, a.z, a.w, b.x, b.y, b.z, b.w};
    const float sfc = 0.35355339059327373f;  // 1/sqrt(8)
    float out[8];
#pragma unroll
    for (int k = 0; k < 8; ++k) {
        float acc = 0.f;
#pragma unroll
        for (int t = 0; t < 8; ++t) acc += emb[t] * sW[t * 8 + k];
        acc *= sfc;
        out[k] = acc / (1.f + __expf(-acc));  // silu
    }
    float4* ph = (float4*)(h + e * 8);
    ph[0] = make_float4(out[0], out[1], out[2], out[3]);
    ph[1] = make_float4(out[4], out[5], out[6], out[7]);
}

// ---------------------------------------------------------------------------
// Kernel 1: per-node linear maps (s1, v1) fused with self-connection einsum.
// sc written directly into out; node_post later adds the W2 term.
// 512 threads, 16 nodes per iteration; LDS 48.25 KB.
// ---------------------------------------------------------------------------
__global__ __launch_bounds__(512) void node_pre_sc(
    const float* __restrict__ nf, const float* __restrict__ attrs,
    const float* __restrict__ W1s, const float* __restrict__ W1v,
    const float* __restrict__ Wscs, const float* __restrict__ Wscv,
    float* __restrict__ s1, float* __restrict__ v1, float* __restrict__ out)
{
    __shared__ float sW1s[1024];
    __shared__ float sW1v[1024];
    __shared__ float sWscs[4096];
    __shared__ float sWscv[4096];
    __shared__ float snf[16][128];
    __shared__ float sat[16][4];
    for (int i = threadIdx.x; i < 1024; i += 512) { sW1s[i] = W1s[i]; sW1v[i] = W1v[i]; }
    for (int i = threadIdx.x; i < 4096; i += 512) { sWscs[i] = Wscs[i]; sWscv[i] = Wscv[i]; }
    int g = threadIdx.x >> 5, v = threadIdx.x & 31;
    const float lin = 0.17677669529663687f;   // 1/sqrt(32)
    const float inv = 0.08838834764831845f;   // 1/sqrt(128)
    for (int node0 = blockIdx.x * 16; node0 < N_NODES; node0 += gridDim.x * 16) {
        __syncthreads();
        for (int i = threadIdx.x; i < 16 * 128; i += 512) {
            int nn = node0 + (i >> 7);
            snf[i >> 7][i & 127] = (nn < N_NODES) ? nf[(long long)nn * 128 + (i & 127)] : 0.f;
        }
        if (threadIdx.x < 64) {
            int nn = node0 + (threadIdx.x >> 2);
            sat[threadIdx.x >> 2][threadIdx.x & 3] = (nn < N_NODES) ? attrs[nn * 4 + (threadIdx.x & 3)] : 0.f;
        }
        __syncthreads();
        int n = node0 + g;
        if (n >= N_NODES) continue;
        float az0 = sat[g][0], az1 = sat[g][1], az2 = sat[g][2], az3 = sat[g][3];
        float acc_s = 0.f, a0 = 0.f, a1 = 0.f, a2 = 0.f;
        float scs = 0.f, scv0 = 0.f, scv1 = 0.f, scv2 = 0.f;
#pragma unroll
        for (int u = 0; u < 32; ++u) {
            float su = snf[g][u];
            float x0 = snf[g][32 + u * 3 + 0];
            float x1 = snf[g][32 + u * 3 + 1];
            float x2 = snf[g][32 + u * 3 + 2];
            acc_s += su * sW1s[u * 32 + v];
            float wv = sW1v[u * 32 + v];
            a0 += x0 * wv; a1 += x1 * wv; a2 += x2 * wv;
            int base = u * 128 + v;
            float cs = az0 * sWscs[base] + az1 * sWscs[base + 32] + az2 * sWscs[base + 64] + az3 * sWscs[base + 96];
            scs += su * cs;
            float cv = az0 * sWscv[base] + az1 * sWscv[base + 32] + az2 * sWscv[base + 64] + az3 * sWscv[base + 96];
            scv0 += x0 * cv; scv1 += x1 * cv; scv2 += x2 * cv;
        }
        s1[(long long)n * 32 + v] = acc_s * lin;
        v1[(long long)n * 96 + v * 3 + 0] = a0 * lin;
        v1[(long long)n * 96 + v * 3 + 1] = a1 * lin;
        v1[(long long)n * 96 + v * 3 + 2] = a2 * lin;
        long long ob = (long long)n * 128;
        out[ob + v] = scs * inv;
        out[ob + 32 + v * 3 + 0] = scv0 * inv;
        out[ob + 32 + v * 3 + 1] = scv1 * inv;
        out[ob + 32 + v * 3 + 2] = scv2 * inv;
    }
}

// ---------------------------------------------------------------------------
// Kernel 2: node-centric gather. No LDS, no block sync. One wave per node.
// UNIFORM trip count T = ceil(deg/2): all 64 lanes execute every trip, so
// every __shfl runs with all lanes active (defined semantics). Per-lane
// validity is the multiplicative predicate m in {0,1} applied to w0..w3;
// shfl source index clamped to a valid entry.
// Writes packed m4[n][64] = (v0, v1, v2, s).
// ---------------------------------------------------------------------------
__global__ __launch_bounds__(256, 4) void gather(
    const int* __restrict__ cnt, const int* __restrict__ list,
    const int* __restrict__ ei,
    const float* __restrict__ h, const float* __restrict__ ea,
    const float* __restrict__ s1, const float* __restrict__ v1,
    const float* __restrict__ Wfc2,
    float4* __restrict__ m4)
{
    int wid = threadIdx.x >> 6;
    int lane = threadIdx.x & 63;
    int u = lane & 31;
    int half = lane >> 5;
    const float sfc = 0.35355339059327373f;  // 1/sqrt(8)
    const float is3 = 0.5773502691896258f;   // 1/sqrt(3)
    // Wfc2 columns for this lane, in registers (pre-scaled).
    float wf0[8], wf1[8], wf2[8], wf3[8];
#pragma unroll
    for (int t = 0; t < 8; ++t) {
        wf0[t] = Wfc2[t * 128 + u] * sfc;
        wf1[t] = Wfc2[t * 128 + 32 + u] * sfc;
        wf2[t] = Wfc2[t * 128 + 64 + u] * sfc;
        wf3[t] = Wfc2[t * 128 + 96 + u] * sfc;
    }
    for (int n = blockIdx.x * 4 + wid; n < N_NODES; n += gridDim.x * 4) {
        int deg = cnt[n];
        if (deg > CAP) deg = CAP;
        int T = (deg + 1) >> 1;  // wave-uniform trip count
        float as0 = 0.f, as3 = 0.f;
        float av10 = 0.f, av11 = 0.f, av12 = 0.f;
        float av20 = 0.f, av21 = 0.f, av22 = 0.f;
        // whole edge list + nbr ids: lane j holds entry j (coalesced loads)
        int e_all = 0, nbr_all = 0;
        if (lane < deg) {
            e_all = list[(long long)n * CAP + lane];
            nbr_all = ei[E_EDGES + e_all];
        }
        float4 hA_c, hB_c, ea_c;
        float xs_c = 0.f, xv0_c = 0.f, xv1_c = 0.f, xv2_c = 0.f, m_c = 0.f;
        if (T > 0) {  // uniform condition
            int j = half;
            m_c = (j < deg) ? 1.f : 0.f;
            int js = (j < deg) ? j : 0;
            int e = __shfl(e_all, js);
            int nbr = __shfl(nbr_all, js);
            const float4* ph = (const float4*)h + (long long)e * 2;
            hA_c = ph[0]; hB_c = ph[1];
            ea_c = ((const float4*)ea)[e];
            xs_c = s1[nbr * 32 + u];
            const float* pv = v1 + nbr * 96 + u * 3;
            xv0_c = pv[0]; xv1_c = pv[1]; xv2_c = pv[2];
        }
        for (int t = 0; t < T; ++t) {
            float4 hA_n, hB_n, ea_n;
            float xs_n = 0.f, xv0_n = 0.f, xv1_n = 0.f, xv2_n = 0.f, m_n = 0.f;
            if (t + 1 < T) {  // uniform condition
                int j = 2 * (t + 1) + half;
                m_n = (j < deg) ? 1.f : 0.f;
                int js = (j < deg) ? j : 0;
                int e = __shfl(e_all, js);
                int nbr = __shfl(nbr_all, js);
                const float4* ph = (const float4*)h + (long long)e * 2;
                hA_n = ph[0]; hB_n = ph[1];
                ea_n = ((const float4*)ea)[e];
                xs_n = s1[nbr * 32 + u];
                const float* pv = v1 + nbr * 96 + u * 3;
                xv0_n = pv[0]; xv1_n = pv[1]; xv2_n = pv[2];
            }
            float hh[8] = {hA_c.x, hA_c.y, hA_c.z, hA_c.w, hB_c.x, hB_c.y, hB_c.z, hB_c.w};
            float w0 = 0.f, w1 = 0.f, w2 = 0.f, w3 = 0.f;
#pragma unroll
            for (int t8 = 0; t8 < 8; ++t8) {
                float ht = hh[t8];
                w0 += ht * wf0[t8];
                w1 += ht * wf1[t8];
                w2 += ht * wf2[t8];
                w3 += ht * wf3[t8];
            }
            w0 *= m_c; w1 *= m_c; w2 *= m_c; w3 *= m_c;
            float es = ea_c.x, ev0 = ea_c.y, ev1 = ea_c.z, ev2 = ea_c.w;
            as0 += w0 * xs_c * es;
            as3 += w3 * (xv0_c * ev0 + xv1_c * ev1 + xv2_c * ev2);
            float t1 = w1 * xs_c;
            float t2 = w2 * es;
            av10 += t1 * ev0; av11 += t1 * ev1; av12 += t1 * ev2;
            av20 += t2 * xv0_c; av21 += t2 * xv1_c; av22 += t2 * xv2_c;
            hA_c = hA_n; hB_c = hB_n; ea_c = ea_n;
            xs_c = xs_n; xv0_c = xv0_n; xv1_c = xv1_n; xv2_c = xv2_n;
            m_c = m_n;
        }
        as0  += __shfl_xor(as0, 32);
        as3  += __shfl_xor(as3, 32);
        av10 += __shfl_xor(av10, 32);
        av11 += __shfl_xor(av11, 32);
        av12 += __shfl_xor(av12, 32);
        av20 += __shfl_xor(av20, 32);
        av21 += __shfl_xor(av21, 32);
        av22 += __shfl_xor(av22, 32);
        if (half == 0) m4[(long long)n * 64 + u]      = make_float4(av10, av11, av12, as0);
        else           m4[(long long)n * 64 + 32 + u] = make_float4(av20, av21, av22, as3 * is3);
    }
}

// ---------------------------------------------------------------------------
// Kernel 3: lean W2 matmul + add into out (sc already there).
// 512 threads, 16 nodes/iter; LDS 32 KB.
// ---------------------------------------------------------------------------
__global__ __launch_bounds__(512) void node_post(
    const float4* __restrict__ m4,
    const float* __restrict__ W2s, const float* __restrict__ W2v,
    float* __restrict__ out)
{
    __shared__ float sW2s[2048];
    __shared__ float sW2v[2048];
    __shared__ float4 sm[16][64];
    for (int i = threadIdx.x; i < 2048; i += 512) { sW2s[i] = W2s[i]; sW2v[i] = W2v[i]; }
    int g = threadIdx.x >> 5, v = threadIdx.x & 31;
    const float lin2 = 0.125f;  // 1/sqrt(64)
    for (int node0 = blockIdx.x * 16; node0 < N_NODES; node0 += gridDim.x * 16) {
        __syncthreads();
        for (int i = threadIdx.x; i < 16 * 64; i += 512) {
            int nn = node0 + (i >> 6);
            sm[i >> 6][i & 63] = (nn < N_NODES) ? m4[(long long)nn * 64 + (i & 63)]
                                                : make_float4(0.f, 0.f, 0.f, 0.f);
        }
        __syncthreads();
        int n = node0 + g;
        if (n >= N_NODES) continue;
        float os = 0.f, ov0 = 0.f, ov1 = 0.f, ov2 = 0.f;
#pragma unroll 16
        for (int U = 0; U < 64; ++U) {
            float4 q = sm[g][U];
            os += q.w * sW2s[U * 32 + v];
            float wv = sW2v[U * 32 + v];
            ov0 += q.x * wv; ov1 += q.y * wv; ov2 += q.z * wv;
        }
        long long ob = (long long)n * 128;
        out[ob + v] += os * lin2;
        out[ob + 32 + v * 3 + 0] += ov0 * lin2;
        out[ob + 32 + v * 3 + 1] += ov1 * lin2;
        out[ob + 32 + v * 3 + 2] += ov2 * lin2;
    }
}

extern "C" void kernel_launch(void* const* d_in, const int* in_sizes, int n_in,
                              void* d_out, int out_size, void* d_ws, size_t ws_size,
                              hipStream_t stream) {
    const float* ee    = (const float*)d_in[0];
    const float* attrs = (const float*)d_in[1];
    const float* nf    = (const float*)d_in[2];
    const int*   ei    = (const int*)d_in[3];
    const float* ea    = (const float*)d_in[4];
    const float* W1s   = (const float*)d_in[5];
    const float* W1v   = (const float*)d_in[6];
    const float* Wfc1  = (const float*)d_in[7];
    const float* Wfc2  = (const float*)d_in[8];
    const float* W2s   = (const float*)d_in[9];
    const float* W2v   = (const float*)d_in[10];
    const float* Wscs  = (const float*)d_in[11];
    const float* Wscv  = (const float*)d_in[12];
    float* out = (float*)d_out;

    float* s1   = (float*)d_ws;                       // N*32
    float* v1   = s1 + (size_t)N_NODES * 32;          // N*96
    float* h    = v1 + (size_t)N_NODES * 96;          // E*8
    float4* m4  = (float4*)(h + (size_t)E_EDGES * 8); // N*64 float4
    int*   cnt  = (int*)(m4 + (size_t)N_NODES * 64);  // N
    int*   list = cnt + N_NODES;                      // N*CAP

    hipMemsetAsync(cnt, 0, (size_t)N_NODES * sizeof(int), stream);
    edge_prep<<<(E_EDGES + 255) / 256, 256, 0, stream>>>(ee, Wfc1, ei, h, cnt, list);
    node_pre_sc<<<768, 512, 0, stream>>>(nf, attrs, W1s, W1v, Wscs, Wscv, s1, v1, out);
    gather<<<1280, 256, 0, stream>>>(cnt, list, ei, h, ea, s1, v1, Wfc2, m4);
    node_post<<<1024, 512, 0, stream>>>(m4, W2s, W2v, out);
}